// Round 6
// baseline (6438.375 us; speedup 1.0000x reference)
//
#include <hip/hip_runtime.h>

typedef unsigned short u16;
typedef unsigned int u32;
typedef __bf16 bf16x8 __attribute__((ext_vector_type(8)));
typedef float f32x4 __attribute__((ext_vector_type(4)));

#define SEQ 4096
#define HM 1536
#define QKVN 4608

__device__ inline u16 f2b(float f){
  u32 u = __builtin_bit_cast(u32, f);
  return (u16)((u + 0x7fffu + ((u>>16)&1u)) >> 16);   // RNE, finite inputs
}
__device__ inline float b2f(u16 h){ return __builtin_bit_cast(float, (u32)h << 16); }
__device__ inline bf16x8 ld8(const u16* p){ return *reinterpret_cast<const bf16x8*>(p); }
__device__ inline void gload16(const void* g, void* l){
  __builtin_amdgcn_global_load_lds((const __attribute__((address_space(1))) void*)g,
                                   (__attribute__((address_space(3))) void*)l, 16, 0, 0);
}

// ---------------- convert fp32 -> bf16 (flat) ----------------
__global__ void cvt_k(const float* __restrict__ in, u16* __restrict__ outp, int n4){
  int i = blockIdx.x*256 + threadIdx.x;
  if (i < n4){
    float4 f = reinterpret_cast<const float4*>(in)[i];
    ushort4 u; u.x=f2b(f.x); u.y=f2b(f.y); u.z=f2b(f.z); u.w=f2b(f.w);
    reinterpret_cast<ushort4*>(outp)[i] = u;
  }
}

// ---------------- transpose+convert W[K][N] f32 -> Wt[N][K] bf16 ----------------
__global__ void tconv(const float* __restrict__ W, u16* __restrict__ Wt, int K, int N){
  __shared__ float tile[32][33];
  int n0 = blockIdx.x*32, k0 = blockIdx.y*32;
  int tx = threadIdx.x, ty = threadIdx.y;            // (32,8)
  #pragma unroll
  for (int i=0;i<4;i++){
    int kk = ty + i*8;
    tile[kk][tx] = W[(size_t)(k0+kk)*N + n0 + tx];
  }
  __syncthreads();
  #pragma unroll
  for (int i=0;i<4;i++){
    int nn = ty + i*8;
    Wt[(size_t)(n0+nn)*K + k0 + tx] = f2b(tile[tx][nn]);
  }
}

// fused Wq/Wk/Wv transpose (all 1536x1536), blockIdx.z selects source
__global__ void tconv3(const float* __restrict__ W0, const float* __restrict__ W1,
                       const float* __restrict__ W2, u16* __restrict__ Wt){
  __shared__ float tile[32][33];
  const float* W = (blockIdx.z==0) ? W0 : (blockIdx.z==1 ? W1 : W2);
  u16* dst = Wt + (size_t)blockIdx.z*1536*1536;
  int n0 = blockIdx.x*32, k0 = blockIdx.y*32;
  int tx = threadIdx.x, ty = threadIdx.y;            // (32,8)
  #pragma unroll
  for (int i=0;i<4;i++){
    int kk = ty + i*8;
    tile[kk][tx] = W[(size_t)(k0+kk)*1536 + n0 + tx];
  }
  __syncthreads();
  #pragma unroll
  for (int i=0;i<4;i++){
    int nn = ty + i*8;
    dst[(size_t)(n0+nn)*1536 + k0 + tx] = f2b(tile[tx][nn]);
  }
}

__global__ void concat3_k(float* __restrict__ dst, const float* __restrict__ a,
                          const float* __restrict__ b, const float* __restrict__ c){
  int i = blockIdx.x*256 + threadIdx.x;
  if (i < 1536){ dst[i]=a[i]; dst[1536+i]=b[i]; dst[3072+i]=c[i]; }
}

// ---------------- GEMM (m97 structure): A[M][K] @ Bt[N][K] bf16, global_load_lds ----
// MODE: 0 QKV (Q,K->qkv; V->vt transposed)  1 plain bf16  2 gelu bf16  3 relu bf16
//       4 plain f32  5 embed f32 (+pos+tok)
template<int MODE>
__global__ __launch_bounds__(256) void gemm_k(
                       const u16* __restrict__ A, const u16* __restrict__ Bt,
                       const float* __restrict__ bias,
                       const float* __restrict__ pos, const float* __restrict__ tok,
                       u16* __restrict__ vtp,
                       u16* __restrict__ outB, float* __restrict__ outF,
                       int M, int N, int K){
  __shared__ __align__(16) u16 As[128*32];
  __shared__ __align__(16) u16 Bs[128*32];
  const int t = threadIdx.x;
  const int m0 = blockIdx.y*128, n0 = blockIdx.x*128;
  const int w = t>>6, l = t&63;
  const int wm = (w>>1)*64, wn = (w&1)*64;
  const int lr = l&15, lg = l>>4;
  const int srow = w*32 + (l>>2);
  const int scol = (l&3)*8;
  const u16* Ap = A  + (size_t)(m0 + srow)*K + scol;
  const u16* Bp = Bt + (size_t)(n0 + srow)*K + scol;
  f32x4 acc[4][4] = {};

  for (int k0 = 0; k0 < K; k0 += 32){
    #pragma unroll
    for (int i=0;i<2;i++){
      gload16(Ap + (size_t)i*16*K + k0, &As[(w*2+i)*512]);
      gload16(Bp + (size_t)i*16*K + k0, &Bs[(w*2+i)*512]);
    }
    __syncthreads();
    bf16x8 af[4], bfr[4];
    #pragma unroll
    for (int i=0;i<4;i++){
      af[i]  = ld8(&As[(wm + i*16 + lr)*32 + lg*8]);
      bfr[i] = ld8(&Bs[(wn + i*16 + lr)*32 + lg*8]);
    }
    #pragma unroll
    for (int i=0;i<4;i++)
      #pragma unroll
      for (int j=0;j<4;j++)
        acc[i][j] = __builtin_amdgcn_mfma_f32_16x16x32_bf16(af[i], bfr[j], acc[i][j], 0,0,0);
    __syncthreads();
  }

  #pragma unroll
  for (int i=0;i<4;i++){
    #pragma unroll
    for (int j=0;j<4;j++){
      int col = n0 + wn + j*16 + lr;
      float bv = bias[col];
      const int row0 = m0 + wm + i*16 + lg*4;
      if (MODE==0 && col >= 3072){
        ushort4 q;
        q.x = f2b(acc[i][j][0] + bv);
        q.y = f2b(acc[i][j][1] + bv);
        q.z = f2b(acc[i][j][2] + bv);
        q.w = f2b(acc[i][j][3] + bv);
        *reinterpret_cast<ushort4*>(&vtp[(size_t)(col-3072)*SEQ + row0]) = q;
        continue;
      }
      #pragma unroll
      for (int r2=0;r2<4;r2++){
        int row = row0 + r2;
        float v = acc[i][j][r2] + bv;
        size_t idx = (size_t)row*N + col;
        if (MODE==0 || MODE==1) outB[idx] = f2b(v);
        else if (MODE==2){
          float g = 0.5f*v*(1.f + tanhf(0.7978845608028654f*(v + 0.044715f*v*v*v)));
          outB[idx] = f2b(g);
        }
        else if (MODE==3) outB[idx] = f2b(fmaxf(v, 0.f));
        else if (MODE==4) outF[idx] = v;
        else if (MODE==5) outF[idx] = v + pos[idx] + tok[col];
      }
    }
  }
}

// ---------------- LayerNorm: row of 1536, block per row ----------------
// RES=0: y = LN(in);  RES=1: y = LN(in + bf16(ga))   (in may alias xf output: row-local)
template<int RES>
__global__ void ln_k(const float* __restrict__ in, const u16* __restrict__ ga,
                     const float* __restrict__ g, const float* __restrict__ bta,
                     float* __restrict__ xf, u16* __restrict__ xb){
  const int row = blockIdx.x, t = threadIdx.x;
  const float2* rp = reinterpret_cast<const float2*>(in + (size_t)row*HM);
  const u32* gp = reinterpret_cast<const u32*>(ga + (size_t)row*HM);
  float2 v[3]; float s=0.f, s2=0.f;
  #pragma unroll
  for (int i=0;i<3;i++){
    v[i] = rp[t + i*256];
    if (RES){
      u32 gw = gp[t + i*256];
      v[i].x += b2f((u16)(gw & 0xffff));
      v[i].y += b2f((u16)(gw >> 16));
    }
    s += v[i].x + v[i].y; s2 += v[i].x*v[i].x + v[i].y*v[i].y;
  }
  #pragma unroll
  for (int o=32;o;o>>=1){ s += __shfl_down(s,o,64); s2 += __shfl_down(s2,o,64); }
  __shared__ float red[8];
  if ((t&63)==0){ red[t>>6]=s; red[4+(t>>6)]=s2; }
  __syncthreads();
  s = red[0]+red[1]+red[2]+red[3]; s2 = red[4]+red[5]+red[6]+red[7];
  float mean = s*(1.f/1536.f);
  float var  = s2*(1.f/1536.f) - mean*mean;
  float inv  = rsqrtf(var + 1e-12f);
  float2* xfp = reinterpret_cast<float2*>(xf + (size_t)row*HM);
  u32*    xbp = reinterpret_cast<u32*>(xb + (size_t)row*HM);
  #pragma unroll
  for (int i=0;i<3;i++){
    int c2 = t + i*256;
    float2 gg = reinterpret_cast<const float2*>(g)[c2];
    float2 bb = reinterpret_cast<const float2*>(bta)[c2];
    float y0 = (v[i].x-mean)*inv*gg.x + bb.x;
    float y1 = (v[i].y-mean)*inv*gg.y + bb.y;
    xfp[c2] = make_float2(y0, y1);
    xbp[c2] = (u32)f2b(y0) | ((u32)f2b(y1) << 16);
  }
}

// ---------------- block-sparse flash attention v3 ----------------
// grid 624: b<496 mid (h=b/62, qb=1+b%62), 2 chunks of 4 kblocks, online softmax,
//           writes ctx directly.
//           b>=496 edge: e=b-496, split=e&7, idx=e>>3, h=idx>>1, qb=idx&1?63:0;
//           kblocks split*8..split*8+7; writes unnormalized (O,m,l) -> tiny LSE merge.
// LDS: sQ [64][200] (2-way-free), sP half-buffer [64][128] XOR-swizzled (16 KB):
//      waves 0,1 write half0 -> PV ks0..3 -> waves 2,3 write half1 -> PV ks4..7.
__device__ inline int sp_off(int row, int colu16){
  return row*128 + ((((colu16)*2) ^ ((row&7)<<4)) >> 1);
}

__global__ __launch_bounds__(256, 3) void attn_k(
    const u16* __restrict__ qkv, const u16* __restrict__ vt,
    const int* __restrict__ kblocks, const int* __restrict__ amask,
    u16* __restrict__ ctx, float* __restrict__ pO,
    float* __restrict__ pm, float* __restrict__ pl){
  __shared__ __align__(16) u16 sQ[64][200];
  __shared__ __align__(16) u16 sP[64*128];
  __shared__ float swm[4][64];
  __shared__ float swl[4][64];
  __shared__ float s_m[64];
  __shared__ float s_l[64];
  __shared__ float s_al[64];

  const int t = threadIdx.x, w = t>>6, l = t&63;
  const int lr = l&15, lg = l>>4;
  const int b = blockIdx.x;
  int h, qb, split;
  bool partial;
  if (b < 496){ h = b/62; qb = 1 + b%62; split = 0; partial = false; }
  else { int e = b-496; split = e&7; int idx = e>>3; h = idx>>1; qb = (idx&1)?63:0; partial = true; }

  {
    const u16* qg = qkv + (size_t)(qb*64)*QKVN + h*192;
    #pragma unroll
    for (int i=0;i<6;i++){
      int idx = t + i*256;            // 0..1535
      int row = idx/24, c8 = idx%24;
      *reinterpret_cast<int4*>(&sQ[row][c8*8]) =
        *reinterpret_cast<const int4*>(qg + (size_t)row*QKVN + c8*8);
    }
  }
  if (t < 64){ s_m[t] = -3.0e38f; s_l[t] = 0.f; }
  __syncthreads();

  f32x4 accO[4][3] = {};
  const float scale = 0.07216878364870323f;   // 1/sqrt(192)

  for (int c = 0; c < 2; ++c){
    int kb4[4];
    #pragma unroll
    for (int i=0;i<4;i++)
      kb4[i] = partial ? (split*8 + c*4 + i) : kblocks[(qb-1)*8 + c*4 + i];
    const int kb = kb4[w];
    // ---- phase A: S = Q K^T for this wave's key-block (64 keys)
    const u16* kp = qkv + (size_t)(kb*64)*QKVN + 1536 + h*192;
    f32x4 acc[4][4] = {};
    #pragma unroll
    for (int d0=0; d0<192; d0+=32){
      bf16x8 aq[4], bk_[4];
      #pragma unroll
      for (int i=0;i<4;i++)  aq[i]  = ld8(&sQ[i*16+lr][d0+lg*8]);
      #pragma unroll
      for (int jn=0;jn<4;jn++) bk_[jn] = ld8(kp + (size_t)(jn*16+lr)*QKVN + d0 + lg*8);
      #pragma unroll
      for (int i=0;i<4;i++)
        #pragma unroll
        for (int jn=0;jn<4;jn++)
          acc[i][jn] = __builtin_amdgcn_mfma_f32_16x16x32_bf16(aq[i], bk_[jn], acc[i][jn], 0,0,0);
    }
    // ---- mask + per-wave row max
    float mcol[4];
    #pragma unroll
    for (int jn=0;jn<4;jn++)
      mcol[jn] = -1e9f*(1.f - (float)amask[kb*64 + jn*16 + lr]);
    #pragma unroll
    for (int i=0;i<4;i++)
      #pragma unroll
      for (int r2=0;r2<4;r2++){
        float mx = -3.0e38f;
        #pragma unroll
        for (int jn=0;jn<4;jn++){
          float sv = acc[i][jn][r2]*scale + mcol[jn];
          acc[i][jn][r2] = sv;
          mx = fmaxf(mx, sv);
        }
        #pragma unroll
        for (int o=1;o<16;o<<=1) mx = fmaxf(mx, __shfl_xor(mx, o, 64));
        if (lr == 0) swm[w][i*16+lg*4+r2] = mx;
      }
    __syncthreads();                       // B1: swm visible
    if (t < 64){
      float mo = s_m[t];
      float mn = fmaxf(fmaxf(fmaxf(swm[0][t], swm[1][t]), fmaxf(swm[2][t], swm[3][t])), mo);
      s_al[t] = __expf(mo - mn);
      s_m[t]  = mn;
    }
    __syncthreads();                       // B2: s_m / s_al visible
    // ---- phase C: p = exp(S-m) in regs; per-wave row sums; rescale O
    #pragma unroll
    for (int i=0;i<4;i++)
      #pragma unroll
      for (int r2=0;r2<4;r2++){
        const int row = i*16 + lg*4 + r2;
        const float mrow = s_m[row];
        float ssum = 0.f;
        #pragma unroll
        for (int jn=0;jn<4;jn++){
          float p = __expf(acc[i][jn][r2] - mrow);
          acc[i][jn][r2] = p;
          ssum += p;
        }
        #pragma unroll
        for (int o=1;o<16;o<<=1) ssum += __shfl_xor(ssum, o, 64);
        if (lr == 0) swl[w][row] = ssum;
      }
    #pragma unroll
    for (int i=0;i<4;i++)
      #pragma unroll
      for (int r2=0;r2<4;r2++){
        float a = s_al[i*16+lg*4+r2];
        #pragma unroll
        for (int jn=0;jn<3;jn++) accO[i][jn][r2] *= a;
      }
    __syncthreads();                       // B3: swl visible; prev PV done -> sP free
    if (t < 64)
      s_l[t] = s_l[t]*s_al[t] + swl[0][t]+swl[1][t]+swl[2][t]+swl[3][t];
    // ---- half 0: waves 0,1 store P (keys 0..127)
    if (w < 2){
      #pragma unroll
      for (int i=0;i<4;i++)
        #pragma unroll
        for (int r2=0;r2<4;r2++){
          const int row = i*16 + lg*4 + r2;
          #pragma unroll
          for (int jn=0;jn<4;jn++)
            sP[sp_off(row, w*64 + jn*16 + lr)] = f2b(acc[i][jn][r2]);
        }
    }
    __syncthreads();                       // B4: half0 visible
    #pragma unroll
    for (int ks=0; ks<4; ks++){
      bf16x8 ap[4], bv_[3];
      #pragma unroll
      for (int i=0;i<4;i++) ap[i] = ld8(&sP[sp_off(i*16+lr, ks*32 + lg*8)]);
      const int sb = kb4[ks>>1]*64 + (ks&1)*32 + lg*8;
      #pragma unroll
      for (int jn=0;jn<3;jn++)
        bv_[jn] = ld8(vt + (size_t)(h*192 + w*48 + jn*16 + lr)*SEQ + sb);
      #pragma unroll
      for (int i=0;i<4;i++)
        #pragma unroll
        for (int jn=0;jn<3;jn++)
          accO[i][jn] = __builtin_amdgcn_mfma_f32_16x16x32_bf16(ap[i], bv_[jn], accO[i][jn], 0,0,0);
    }
    __syncthreads();                       // B5: PV half0 done
    // ---- half 1: waves 2,3 store P (keys 128..255)
    if (w >= 2){
      #pragma unroll
      for (int i=0;i<4;i++)
        #pragma unroll
        for (int r2=0;r2<4;r2++){
          const int row = i*16 + lg*4 + r2;
          #pragma unroll
          for (int jn=0;jn<4;jn++)
            sP[sp_off(row, (w-2)*64 + jn*16 + lr)] = f2b(acc[i][jn][r2]);
        }
    }
    __syncthreads();                       // B6: half1 visible
    #pragma unroll
    for (int ks=4; ks<8; ks++){
      bf16x8 ap[4], bv_[3];
      #pragma unroll
      for (int i=0;i<4;i++) ap[i] = ld8(&sP[sp_off(i*16+lr, (ks-4)*32 + lg*8)]);
      const int sb = kb4[ks>>1]*64 + (ks&1)*32 + lg*8;
      #pragma unroll
      for (int jn=0;jn<3;jn++)
        bv_[jn] = ld8(vt + (size_t)(h*192 + w*48 + jn*16 + lr)*SEQ + sb);
      #pragma unroll
      for (int i=0;i<4;i++)
        #pragma unroll
        for (int jn=0;jn<3;jn++)
          accO[i][jn] = __builtin_amdgcn_mfma_f32_16x16x32_bf16(ap[i], bv_[jn], accO[i][jn], 0,0,0);
    }
    __syncthreads();                       // B7: PV half1 done (sP reusable next chunk)
  }
  if (!partial){
    #pragma unroll
    for (int i=0;i<4;i++)
      #pragma unroll
      for (int r2=0;r2<4;r2++){
        const int row = i*16+lg*4+r2;
        const float inv = 1.f / s_l[row];
        #pragma unroll
        for (int jn=0;jn<3;jn++){
          const int col = h*192 + w*48 + jn*16 + lr;
          ctx[(size_t)(qb*64+row)*HM + col] = f2b(accO[i][jn][r2] * inv);
        }
      }
  } else {
    const int e = b - 496;
    #pragma unroll
    for (int i=0;i<4;i++)
      #pragma unroll
      for (int r2=0;r2<4;r2++){
        const int row = i*16+lg*4+r2;
        #pragma unroll
        for (int jn=0;jn<3;jn++){
          const int col = w*48 + jn*16 + lr;
          pO[((size_t)e*64 + row)*192 + col] = accO[i][jn][r2];
        }
      }
    if (t < 64){ pm[e*64 + t] = s_m[t]; pl[e*64 + t] = s_l[t]; }
  }
}

// merge 8 key-range splits for the 16 edge (h,qb) tiles
__global__ void attn_comb_k(const float* __restrict__ pO, const float* __restrict__ pm,
                            const float* __restrict__ pl, u16* __restrict__ ctx){
  const int bidx = blockIdx.x;         // 0..15
  const int h = bidx>>1, qb = (bidx&1)?63:0;
  const int t = threadIdx.x;
  __shared__ float sA[8][64];
  __shared__ float sInv[64];
  if (t < 64){
    float M = -3.0e38f;
    #pragma unroll
    for (int s=0;s<8;s++) M = fmaxf(M, pm[(bidx*8+s)*64 + t]);
    float L = 0.f;
    #pragma unroll
    for (int s=0;s<8;s++){
      float a = __expf(pm[(bidx*8+s)*64 + t] - M);
      sA[s][t] = a;
      L += pl[(bidx*8+s)*64 + t]*a;
    }
    sInv[t] = 1.f/L;
  }
  __syncthreads();
  #pragma unroll
  for (int i=0;i<48;i++){
    int idx = t + i*256;               // 0..12287
    int row = idx/192, col = idx%192;
    float acc = 0.f;
    #pragma unroll
    for (int s=0;s<8;s++)
      acc += sA[s][row] * pO[((size_t)(bidx*8+s)*64 + row)*192 + col];
    ctx[(size_t)(qb*64+row)*HM + h*192 + col] = f2b(acc * sInv[row]);
  }
}

// =====================================================================
extern "C" void kernel_launch(void* const* d_in, const int* in_sizes, int n_in,
                              void* d_out, int out_size, void* d_ws, size_t ws_size,
                              hipStream_t stream){
  const float* x       = (const float*)d_in[0];
  const float* proj_w  = (const float*)d_in[1];
  const float* proj_b  = (const float*)d_in[2];
  const float* pos_emb = (const float*)d_in[3];
  const float* tok_emb = (const float*)d_in[4];
  const float* embs    = (const float*)d_in[5];
  const float* embb    = (const float*)d_in[6];
  const float* Wq  = (const float*)d_in[7];
  const float* bq  = (const float*)d_in[8];
  const float* Wk  = (const float*)d_in[9];
  const float* bk  = (const float*)d_in[10];
  const float* Wv  = (const float*)d_in[11];
  const float* bv  = (const float*)d_in[12];
  const float* Wo  = (const float*)d_in[13];
  const float* bo  = (const float*)d_in[14];
  const float* l1s = (const float*)d_in[15];
  const float* l1b = (const float*)d_in[16];
  const float* Wi  = (const float*)d_in[17];
  const float* bi  = (const float*)d_in[18];
  const float* Wo2 = (const float*)d_in[19];
  const float* bo2 = (const float*)d_in[20];
  const float* l2s = (const float*)d_in[21];
  const float* l2b = (const float*)d_in[22];
  const float* cw1 = (const float*)d_in[23];
  const float* cb1 = (const float*)d_in[24];
  const float* cw2 = (const float*)d_in[25];
  const float* cb2 = (const float*)d_in[26];
  const int* amask = (const int*)d_in[27];
  const int* kblk  = (const int*)d_in[28];
  float* out = (float*)d_out;

  char* base = (char*)d_ws;
  size_t off = 0;
  auto carve = [&](size_t bytes)->char*{
    char* p = base + off; off += (bytes + 255) & ~(size_t)255; return p;
  };
  float* xf32  = (float*)carve(4096ULL*1536*4);
  u16*   xbf   = (u16*)  carve(4096ULL*1536*2);
  u16*   xinbf = (u16*)  carve(4096ULL*1280*2);
  u16*   qkv   = (u16*)  carve(4096ULL*4608*2);
  u16*   vt    = (u16*)  carve(1536ULL*4096*2);
  u16*   ctx   = (u16*)  carve(4096ULL*1536*2);
  u16*   go    = (u16*)  carve(4096ULL*1536*2);
  u16*   ff1   = (u16*)  carve(4096ULL*3072*2);
  u16*   cls1  = (u16*)  carve(4096ULL*512*2);
  u16*   wt    = (u16*)  carve(4608ULL*1536*2);
  float* b3    = (float*)carve(4608ULL*4);
  float* pO    = (float*)carve(128ULL*64*192*4);
  float* pm    = (float*)carve(128ULL*64*4);
  float* pl    = (float*)carve(128ULL*64*4);
  if (off > ws_size) return;   // workspace too small: fail cleanly

  const dim3 tb32(32,8);

  // ---- embedding ----
  cvt_k<<<5120, 256, 0, stream>>>(x, xinbf, 4096*1280/4);
  tconv<<<dim3(48,40), tb32, 0, stream>>>(proj_w, wt, 1280, 1536);
  gemm_k<5><<<dim3(12,32), 256, 0, stream>>>(xinbf, wt, proj_b, pos_emb, tok_emb,
                                             nullptr, nullptr, xf32, 4096, 1536, 1280);
  ln_k<0><<<4096, 256, 0, stream>>>(xf32, xbf /*unused*/, embs, embb, xf32, xbf);

  // ---- encoder layers ----
  for (int l = 0; l < 12; ++l){
    const float* wq  = Wq  + (size_t)l*1536*1536;
    const float* wk  = Wk  + (size_t)l*1536*1536;
    const float* wv  = Wv  + (size_t)l*1536*1536;
    const float* wo  = Wo  + (size_t)l*1536*1536;
    const float* wi  = Wi  + (size_t)l*1536*3072;
    const float* wo2 = Wo2 + (size_t)l*3072*1536;
    const float* bql = bq  + (size_t)l*1536;
    const float* bkl = bk  + (size_t)l*1536;
    const float* bvl = bv  + (size_t)l*1536;
    const float* bol = bo  + (size_t)l*1536;
    const float* bil = bi  + (size_t)l*3072;
    const float* bo2l= bo2 + (size_t)l*1536;
    const float* g1  = l1s + (size_t)l*1536;
    const float* be1 = l1b + (size_t)l*1536;
    const float* g2  = l2s + (size_t)l*1536;
    const float* be2 = l2b + (size_t)l*1536;

    // fused QKV (V written transposed to vt in epilogue)
    tconv3<<<dim3(48,48,3), tb32, 0, stream>>>(wq, wk, wv, wt);
    concat3_k<<<6, 256, 0, stream>>>(b3, bql, bkl, bvl);
    gemm_k<0><<<dim3(36,32), 256, 0, stream>>>(xbf, wt, b3, nullptr, nullptr,
                                               vt, qkv, nullptr, 4096, 4608, 1536);

    // block-sparse attention: mids direct, edges split-K + LSE merge
    attn_k<<<624, 256, 0, stream>>>(qkv, vt, kblk, amask, ctx, pO, pm, pl);
    attn_comb_k<<<16, 256, 0, stream>>>(pO, pm, pl, ctx);

    // attention output projection (plain bf16) + fused residual LN
    tconv<<<dim3(48,48), tb32, 0, stream>>>(wo, wt, 1536, 1536);
    gemm_k<1><<<dim3(12,32), 256, 0, stream>>>(ctx, wt, bol, nullptr, nullptr,
                                               nullptr, go, nullptr, 4096, 1536, 1536);
    ln_k<1><<<4096, 256, 0, stream>>>(xf32, go, g1, be1, xf32, xbf);

    // FFN
    tconv<<<dim3(96,48), tb32, 0, stream>>>(wi, wt, 1536, 3072);
    gemm_k<2><<<dim3(24,32), 256, 0, stream>>>(xbf, wt, bil, nullptr, nullptr,
                                               nullptr, ff1, nullptr, 4096, 3072, 1536);
    tconv<<<dim3(48,96), tb32, 0, stream>>>(wo2, wt, 3072, 1536);
    gemm_k<1><<<dim3(12,32), 256, 0, stream>>>(ff1, wt, bo2l, nullptr, nullptr,
                                               nullptr, go, nullptr, 4096, 1536, 3072);
    ln_k<1><<<4096, 256, 0, stream>>>(xf32, go, g2, be2, xf32, xbf);
  }

  // ---- classifier head ----
  tconv<<<dim3(16,48), tb32, 0, stream>>>(cw1, wt, 1536, 512);
  gemm_k<3><<<dim3(4,32), 256, 0, stream>>>(xbf, wt, cb1, nullptr, nullptr,
                                            nullptr, cls1, nullptr, 4096, 512, 1536);
  tconv<<<dim3(8,16), tb32, 0, stream>>>(cw2, wt, 512, 256);
  gemm_k<4><<<dim3(2,32), 256, 0, stream>>>(cls1, wt, cb2, nullptr, nullptr,
                                            nullptr, nullptr, out, 4096, 256, 512);

  (void)in_sizes; (void)n_in; (void)out_size;
}

// Round 7
// 5352.840 us; speedup vs baseline: 1.2028x; 1.2028x over previous
//
#include <hip/hip_runtime.h>

typedef unsigned short u16;
typedef unsigned int u32;
typedef __bf16 bf16x8 __attribute__((ext_vector_type(8)));
typedef float f32x4 __attribute__((ext_vector_type(4)));

#define SEQ 4096
#define HM 1536
#define QKVN 4608

__device__ inline u16 f2b(float f){
  u32 u = __builtin_bit_cast(u32, f);
  return (u16)((u + 0x7fffu + ((u>>16)&1u)) >> 16);   // RNE, finite inputs
}
__device__ inline float b2f(u16 h){ return __builtin_bit_cast(float, (u32)h << 16); }
__device__ inline bf16x8 ld8(const u16* p){ return *reinterpret_cast<const bf16x8*>(p); }
__device__ inline void gload16(const void* g, void* l){
  __builtin_amdgcn_global_load_lds((const __attribute__((address_space(1))) void*)g,
                                   (__attribute__((address_space(3))) void*)l, 16, 0, 0);
}

// ---------------- convert fp32 -> bf16 (flat) ----------------
__global__ void cvt_k(const float* __restrict__ in, u16* __restrict__ outp, int n4){
  int i = blockIdx.x*256 + threadIdx.x;
  if (i < n4){
    float4 f = reinterpret_cast<const float4*>(in)[i];
    ushort4 u; u.x=f2b(f.x); u.y=f2b(f.y); u.z=f2b(f.z); u.w=f2b(f.w);
    reinterpret_cast<ushort4*>(outp)[i] = u;
  }
}

// ---------------- transpose+convert W[K][N] f32 -> Wt[N][K] bf16 ----------------
__global__ void tconv(const float* __restrict__ W, u16* __restrict__ Wt, int K, int N){
  __shared__ float tile[32][33];
  int n0 = blockIdx.x*32, k0 = blockIdx.y*32;
  int tx = threadIdx.x, ty = threadIdx.y;            // (32,8)
  #pragma unroll
  for (int i=0;i<4;i++){
    int kk = ty + i*8;
    tile[kk][tx] = W[(size_t)(k0+kk)*N + n0 + tx];
  }
  __syncthreads();
  #pragma unroll
  for (int i=0;i<4;i++){
    int nn = ty + i*8;
    Wt[(size_t)(n0+nn)*K + k0 + tx] = f2b(tile[tx][nn]);
  }
}

// fused Wq/Wk/Wv transpose (all 1536x1536), blockIdx.z selects source
__global__ void tconv3(const float* __restrict__ W0, const float* __restrict__ W1,
                       const float* __restrict__ W2, u16* __restrict__ Wt){
  __shared__ float tile[32][33];
  const float* W = (blockIdx.z==0) ? W0 : (blockIdx.z==1 ? W1 : W2);
  u16* dst = Wt + (size_t)blockIdx.z*1536*1536;
  int n0 = blockIdx.x*32, k0 = blockIdx.y*32;
  int tx = threadIdx.x, ty = threadIdx.y;            // (32,8)
  #pragma unroll
  for (int i=0;i<4;i++){
    int kk = ty + i*8;
    tile[kk][tx] = W[(size_t)(k0+kk)*1536 + n0 + tx];
  }
  __syncthreads();
  #pragma unroll
  for (int i=0;i<4;i++){
    int nn = ty + i*8;
    dst[(size_t)(n0+nn)*1536 + k0 + tx] = f2b(tile[tx][nn]);
  }
}

__global__ void concat3_k(float* __restrict__ dst, const float* __restrict__ a,
                          const float* __restrict__ b, const float* __restrict__ c){
  int i = blockIdx.x*256 + threadIdx.x;
  if (i < 1536){ dst[i]=a[i]; dst[1536+i]=b[i]; dst[3072+i]=c[i]; }
}

// ---------------- GEMM (m97 structure): A[M][K] @ Bt[N][K] bf16, global_load_lds ----
// MODE: 0 QKV (Q,K->qkv; V->vt transposed)  1 plain bf16  2 gelu bf16  3 relu bf16
//       4 plain f32  5 embed f32 (+pos+tok)
template<int MODE>
__global__ __launch_bounds__(256) void gemm_k(
                       const u16* __restrict__ A, const u16* __restrict__ Bt,
                       const float* __restrict__ bias,
                       const float* __restrict__ pos, const float* __restrict__ tok,
                       u16* __restrict__ vtp,
                       u16* __restrict__ outB, float* __restrict__ outF,
                       int M, int N, int K){
  __shared__ __align__(16) u16 As[128*32];
  __shared__ __align__(16) u16 Bs[128*32];
  const int t = threadIdx.x;
  const int m0 = blockIdx.y*128, n0 = blockIdx.x*128;
  const int w = t>>6, l = t&63;
  const int wm = (w>>1)*64, wn = (w&1)*64;
  const int lr = l&15, lg = l>>4;
  const int srow = w*32 + (l>>2);
  const int scol = (l&3)*8;
  const u16* Ap = A  + (size_t)(m0 + srow)*K + scol;
  const u16* Bp = Bt + (size_t)(n0 + srow)*K + scol;
  f32x4 acc[4][4] = {};

  for (int k0 = 0; k0 < K; k0 += 32){
    #pragma unroll
    for (int i=0;i<2;i++){
      gload16(Ap + (size_t)i*16*K + k0, &As[(w*2+i)*512]);
      gload16(Bp + (size_t)i*16*K + k0, &Bs[(w*2+i)*512]);
    }
    __syncthreads();
    bf16x8 af[4], bfr[4];
    #pragma unroll
    for (int i=0;i<4;i++){
      af[i]  = ld8(&As[(wm + i*16 + lr)*32 + lg*8]);
      bfr[i] = ld8(&Bs[(wn + i*16 + lr)*32 + lg*8]);
    }
    #pragma unroll
    for (int i=0;i<4;i++)
      #pragma unroll
      for (int j=0;j<4;j++)
        acc[i][j] = __builtin_amdgcn_mfma_f32_16x16x32_bf16(af[i], bfr[j], acc[i][j], 0,0,0);
    __syncthreads();
  }

  #pragma unroll
  for (int i=0;i<4;i++){
    #pragma unroll
    for (int j=0;j<4;j++){
      int col = n0 + wn + j*16 + lr;
      float bv = bias[col];
      const int row0 = m0 + wm + i*16 + lg*4;
      if (MODE==0 && col >= 3072){
        ushort4 q;
        q.x = f2b(acc[i][j][0] + bv);
        q.y = f2b(acc[i][j][1] + bv);
        q.z = f2b(acc[i][j][2] + bv);
        q.w = f2b(acc[i][j][3] + bv);
        *reinterpret_cast<ushort4*>(&vtp[(size_t)(col-3072)*SEQ + row0]) = q;
        continue;
      }
      #pragma unroll
      for (int r2=0;r2<4;r2++){
        int row = row0 + r2;
        float v = acc[i][j][r2] + bv;
        size_t idx = (size_t)row*N + col;
        if (MODE==0 || MODE==1) outB[idx] = f2b(v);
        else if (MODE==2){
          float g = 0.5f*v*(1.f + tanhf(0.7978845608028654f*(v + 0.044715f*v*v*v)));
          outB[idx] = f2b(g);
        }
        else if (MODE==3) outB[idx] = f2b(fmaxf(v, 0.f));
        else if (MODE==4) outF[idx] = v;
        else if (MODE==5) outF[idx] = v + pos[idx] + tok[col];
      }
    }
  }
}

// ---------------- LayerNorm: row of 1536, block per row ----------------
// RES=0: y = LN(in);  RES=1: y = LN(in + bf16(ga))   (in may alias xf output: row-local)
template<int RES>
__global__ void ln_k(const float* __restrict__ in, const u16* __restrict__ ga,
                     const float* __restrict__ g, const float* __restrict__ bta,
                     float* __restrict__ xf, u16* __restrict__ xb){
  const int row = blockIdx.x, t = threadIdx.x;
  const float2* rp = reinterpret_cast<const float2*>(in + (size_t)row*HM);
  const u32* gp = reinterpret_cast<const u32*>(ga + (size_t)row*HM);
  float2 v[3]; float s=0.f, s2=0.f;
  #pragma unroll
  for (int i=0;i<3;i++){
    v[i] = rp[t + i*256];
    if (RES){
      u32 gw = gp[t + i*256];
      v[i].x += b2f((u16)(gw & 0xffff));
      v[i].y += b2f((u16)(gw >> 16));
    }
    s += v[i].x + v[i].y; s2 += v[i].x*v[i].x + v[i].y*v[i].y;
  }
  #pragma unroll
  for (int o=32;o;o>>=1){ s += __shfl_down(s,o,64); s2 += __shfl_down(s2,o,64); }
  __shared__ float red[8];
  if ((t&63)==0){ red[t>>6]=s; red[4+(t>>6)]=s2; }
  __syncthreads();
  s = red[0]+red[1]+red[2]+red[3]; s2 = red[4]+red[5]+red[6]+red[7];
  float mean = s*(1.f/1536.f);
  float var  = s2*(1.f/1536.f) - mean*mean;
  float inv  = rsqrtf(var + 1e-12f);
  float2* xfp = reinterpret_cast<float2*>(xf + (size_t)row*HM);
  u32*    xbp = reinterpret_cast<u32*>(xb + (size_t)row*HM);
  #pragma unroll
  for (int i=0;i<3;i++){
    int c2 = t + i*256;
    float2 gg = reinterpret_cast<const float2*>(g)[c2];
    float2 bb = reinterpret_cast<const float2*>(bta)[c2];
    float y0 = (v[i].x-mean)*inv*gg.x + bb.x;
    float y1 = (v[i].y-mean)*inv*gg.y + bb.y;
    xfp[c2] = make_float2(y0, y1);
    xbp[c2] = (u32)f2b(y0) | ((u32)f2b(y1) << 16);
  }
}

// ---------------- block-sparse flash attention (R3 structure, no spill) ----------------
// grid 624: b<496 mid (h=b/62, qb=1+b%62): 2 chunks of 4 kblocks, online softmax,
//           writes ctx directly.  b>=496 edge: split-K over 8 key ranges -> (O,m,l).
// Full sP [64*256] XOR-swizzled; all waves write P right after exp (acc dies before PV).
__device__ inline int sp_off(int row, int colu16){
  return row*256 + ((((colu16)*2) ^ ((row&7)<<4)) >> 1);
}

__global__ __launch_bounds__(256, 2) void attn_k(
    const u16* __restrict__ qkv, const u16* __restrict__ vt,
    const int* __restrict__ kblocks, const int* __restrict__ amask,
    u16* __restrict__ ctx, float* __restrict__ pO,
    float* __restrict__ pm, float* __restrict__ pl){
  __shared__ __align__(16) u16 sQ[64][200];
  __shared__ __align__(16) u16 sP[64*256];
  __shared__ float swm[4][64];
  __shared__ float swl[4][64];
  __shared__ float s_m[64];
  __shared__ float s_l[64];
  __shared__ float s_al[64];

  const int t = threadIdx.x, w = t>>6, l = t&63;
  const int lr = l&15, lg = l>>4;
  const int b = blockIdx.x;
  int h, qb, split;
  bool partial;
  if (b < 496){ h = b/62; qb = 1 + b%62; split = 0; partial = false; }
  else { int e = b-496; split = e&7; int idx = e>>3; h = idx>>1; qb = (idx&1)?63:0; partial = true; }

  {
    const u16* qg = qkv + (size_t)(qb*64)*QKVN + h*192;
    #pragma unroll
    for (int i=0;i<6;i++){
      int idx = t + i*256;            // 0..1535
      int row = idx/24, c8 = idx%24;
      *reinterpret_cast<int4*>(&sQ[row][c8*8]) =
        *reinterpret_cast<const int4*>(qg + (size_t)row*QKVN + c8*8);
    }
  }
  if (t < 64){ s_m[t] = -3.0e38f; s_l[t] = 0.f; }
  __syncthreads();

  f32x4 accO[4][3] = {};
  const float scale = 0.07216878364870323f;   // 1/sqrt(192)

  for (int c = 0; c < 2; ++c){
    int kb4[4];
    #pragma unroll
    for (int i=0;i<4;i++)
      kb4[i] = partial ? (split*8 + c*4 + i) : kblocks[(qb-1)*8 + c*4 + i];
    const int kb = kb4[w];
    // ---- phase A: S = Q K^T for this wave's key-block (64 keys)
    const u16* kp = qkv + (size_t)(kb*64)*QKVN + 1536 + h*192;
    f32x4 acc[4][4] = {};
    #pragma unroll
    for (int d0=0; d0<192; d0+=32){
      bf16x8 aq[4], bk_[4];
      #pragma unroll
      for (int i=0;i<4;i++)  aq[i]  = ld8(&sQ[i*16+lr][d0+lg*8]);
      #pragma unroll
      for (int jn=0;jn<4;jn++) bk_[jn] = ld8(kp + (size_t)(jn*16+lr)*QKVN + d0 + lg*8);
      #pragma unroll
      for (int i=0;i<4;i++)
        #pragma unroll
        for (int jn=0;jn<4;jn++)
          acc[i][jn] = __builtin_amdgcn_mfma_f32_16x16x32_bf16(aq[i], bk_[jn], acc[i][jn], 0,0,0);
    }
    // ---- mask + per-wave row max
    float mcol[4];
    #pragma unroll
    for (int jn=0;jn<4;jn++)
      mcol[jn] = -1e9f*(1.f - (float)amask[kb*64 + jn*16 + lr]);
    #pragma unroll
    for (int i=0;i<4;i++)
      #pragma unroll
      for (int r2=0;r2<4;r2++){
        float mx = -3.0e38f;
        #pragma unroll
        for (int jn=0;jn<4;jn++){
          float sv = acc[i][jn][r2]*scale + mcol[jn];
          acc[i][jn][r2] = sv;
          mx = fmaxf(mx, sv);
        }
        #pragma unroll
        for (int o=1;o<16;o<<=1) mx = fmaxf(mx, __shfl_xor(mx, o, 64));
        if (lr == 0) swm[w][i*16+lg*4+r2] = mx;
      }
    __syncthreads();                       // B1: swm visible; prev PV done -> sP free
    if (t < 64){
      float mo = s_m[t];
      float mn = fmaxf(fmaxf(fmaxf(swm[0][t], swm[1][t]), fmaxf(swm[2][t], swm[3][t])), mo);
      s_al[t] = __expf(mo - mn);
      s_m[t]  = mn;
    }
    __syncthreads();                       // B2: s_m / s_al visible
    // ---- phase C: P = exp(S-m) -> sP bf16 (swizzled); partial sums; rescale O
    #pragma unroll
    for (int i=0;i<4;i++)
      #pragma unroll
      for (int r2=0;r2<4;r2++){
        const int row = i*16 + lg*4 + r2;
        const float mrow = s_m[row];
        float ssum = 0.f;
        #pragma unroll
        for (int jn=0;jn<4;jn++){
          float p = __expf(acc[i][jn][r2] - mrow);
          ssum += p;
          sP[sp_off(row, w*64 + jn*16 + lr)] = f2b(p);
        }
        #pragma unroll
        for (int o=1;o<16;o<<=1) ssum += __shfl_xor(ssum, o, 64);
        if (lr == 0) swl[w][row] = ssum;
      }
    #pragma unroll
    for (int i=0;i<4;i++)
      #pragma unroll
      for (int r2=0;r2<4;r2++){
        float a = s_al[i*16+lg*4+r2];
        #pragma unroll
        for (int jn=0;jn<3;jn++) accO[i][jn][r2] *= a;
      }
    __syncthreads();                       // B3: sP / swl visible
    if (t < 64)
      s_l[t] = s_l[t]*s_al[t] + swl[0][t]+swl[1][t]+swl[2][t]+swl[3][t];
    // ---- phase E: O += P V (wave's 48 output dims, 256 chunk keys)
    #pragma unroll
    for (int ks=0; ks<8; ks++){
      bf16x8 ap[4], bv_[3];
      #pragma unroll
      for (int i=0;i<4;i++) ap[i] = ld8(&sP[sp_off(i*16+lr, ks*32 + lg*8)]);
      const int sb = kb4[ks>>1]*64 + (ks&1)*32 + lg*8;
      #pragma unroll
      for (int jn=0;jn<3;jn++)
        bv_[jn] = ld8(vt + (size_t)(h*192 + w*48 + jn*16 + lr)*SEQ + sb);
      #pragma unroll
      for (int i=0;i<4;i++)
        #pragma unroll
        for (int jn=0;jn<3;jn++)
          accO[i][jn] = __builtin_amdgcn_mfma_f32_16x16x32_bf16(ap[i], bv_[jn], accO[i][jn], 0,0,0);
    }
  }
  __syncthreads();
  if (!partial){
    #pragma unroll
    for (int i=0;i<4;i++)
      #pragma unroll
      for (int r2=0;r2<4;r2++){
        const int row = i*16+lg*4+r2;
        const float inv = 1.f / s_l[row];
        #pragma unroll
        for (int jn=0;jn<3;jn++){
          const int col = h*192 + w*48 + jn*16 + lr;
          ctx[(size_t)(qb*64+row)*HM + col] = f2b(accO[i][jn][r2] * inv);
        }
      }
  } else {
    const int e = b - 496;
    #pragma unroll
    for (int i=0;i<4;i++)
      #pragma unroll
      for (int r2=0;r2<4;r2++){
        const int row = i*16+lg*4+r2;
        #pragma unroll
        for (int jn=0;jn<3;jn++){
          const int col = w*48 + jn*16 + lr;
          pO[((size_t)e*64 + row)*192 + col] = accO[i][jn][r2];
        }
      }
    if (t < 64){ pm[e*64 + t] = s_m[t]; pl[e*64 + t] = s_l[t]; }
  }
}

// merge 8 key-range splits for the 16 edge (h,qb) tiles
__global__ void attn_comb_k(const float* __restrict__ pO, const float* __restrict__ pm,
                            const float* __restrict__ pl, u16* __restrict__ ctx){
  const int bidx = blockIdx.x;         // 0..15
  const int h = bidx>>1, qb = (bidx&1)?63:0;
  const int t = threadIdx.x;
  __shared__ float sA[8][64];
  __shared__ float sInv[64];
  if (t < 64){
    float M = -3.0e38f;
    #pragma unroll
    for (int s=0;s<8;s++) M = fmaxf(M, pm[(bidx*8+s)*64 + t]);
    float L = 0.f;
    #pragma unroll
    for (int s=0;s<8;s++){
      float a = __expf(pm[(bidx*8+s)*64 + t] - M);
      sA[s][t] = a;
      L += pl[(bidx*8+s)*64 + t]*a;
    }
    sInv[t] = 1.f/L;
  }
  __syncthreads();
  #pragma unroll
  for (int i=0;i<48;i++){
    int idx = t + i*256;               // 0..12287
    int row = idx/192, col = idx%192;
    float acc = 0.f;
    #pragma unroll
    for (int s=0;s<8;s++)
      acc += sA[s][row] * pO[((size_t)(bidx*8+s)*64 + row)*192 + col];
    ctx[(size_t)(qb*64+row)*HM + h*192 + col] = f2b(acc * sInv[row]);
  }
}

// =====================================================================
extern "C" void kernel_launch(void* const* d_in, const int* in_sizes, int n_in,
                              void* d_out, int out_size, void* d_ws, size_t ws_size,
                              hipStream_t stream){
  const float* x       = (const float*)d_in[0];
  const float* proj_w  = (const float*)d_in[1];
  const float* proj_b  = (const float*)d_in[2];
  const float* pos_emb = (const float*)d_in[3];
  const float* tok_emb = (const float*)d_in[4];
  const float* embs    = (const float*)d_in[5];
  const float* embb    = (const float*)d_in[6];
  const float* Wq  = (const float*)d_in[7];
  const float* bq  = (const float*)d_in[8];
  const float* Wk  = (const float*)d_in[9];
  const float* bk  = (const float*)d_in[10];
  const float* Wv  = (const float*)d_in[11];
  const float* bv  = (const float*)d_in[12];
  const float* Wo  = (const float*)d_in[13];
  const float* bo  = (const float*)d_in[14];
  const float* l1s = (const float*)d_in[15];
  const float* l1b = (const float*)d_in[16];
  const float* Wi  = (const float*)d_in[17];
  const float* bi  = (const float*)d_in[18];
  const float* Wo2 = (const float*)d_in[19];
  const float* bo2 = (const float*)d_in[20];
  const float* l2s = (const float*)d_in[21];
  const float* l2b = (const float*)d_in[22];
  const float* cw1 = (const float*)d_in[23];
  const float* cb1 = (const float*)d_in[24];
  const float* cw2 = (const float*)d_in[25];
  const float* cb2 = (const float*)d_in[26];
  const int* amask = (const int*)d_in[27];
  const int* kblk  = (const int*)d_in[28];
  float* out = (float*)d_out;

  char* base = (char*)d_ws;
  size_t off = 0;
  auto carve = [&](size_t bytes)->char*{
    char* p = base + off; off += (bytes + 255) & ~(size_t)255; return p;
  };
  float* xf32  = (float*)carve(4096ULL*1536*4);
  u16*   xbf   = (u16*)  carve(4096ULL*1536*2);
  u16*   xinbf = (u16*)  carve(4096ULL*1280*2);
  u16*   qkv   = (u16*)  carve(4096ULL*4608*2);
  u16*   vt    = (u16*)  carve(1536ULL*4096*2);
  u16*   ctx   = (u16*)  carve(4096ULL*1536*2);
  u16*   go    = (u16*)  carve(4096ULL*1536*2);
  u16*   ff1   = (u16*)  carve(4096ULL*3072*2);
  u16*   cls1  = (u16*)  carve(4096ULL*512*2);
  u16*   wt    = (u16*)  carve(4608ULL*1536*2);
  float* b3    = (float*)carve(4608ULL*4);
  float* pO    = (float*)carve(128ULL*64*192*4);
  float* pm    = (float*)carve(128ULL*64*4);
  float* pl    = (float*)carve(128ULL*64*4);
  if (off > ws_size) return;   // workspace too small: fail cleanly

  const dim3 tb32(32,8);

  // ---- embedding ----
  cvt_k<<<5120, 256, 0, stream>>>(x, xinbf, 4096*1280/4);
  tconv<<<dim3(48,40), tb32, 0, stream>>>(proj_w, wt, 1280, 1536);
  gemm_k<5><<<dim3(12,32), 256, 0, stream>>>(xinbf, wt, proj_b, pos_emb, tok_emb,
                                             nullptr, nullptr, xf32, 4096, 1536, 1280);
  ln_k<0><<<4096, 256, 0, stream>>>(xf32, xbf /*unused*/, embs, embb, xf32, xbf);

  // ---- encoder layers ----
  for (int l = 0; l < 12; ++l){
    const float* wq  = Wq  + (size_t)l*1536*1536;
    const float* wk  = Wk  + (size_t)l*1536*1536;
    const float* wv  = Wv  + (size_t)l*1536*1536;
    const float* wo  = Wo  + (size_t)l*1536*1536;
    const float* wi  = Wi  + (size_t)l*1536*3072;
    const float* wo2 = Wo2 + (size_t)l*3072*1536;
    const float* bql = bq  + (size_t)l*1536;
    const float* bkl = bk  + (size_t)l*1536;
    const float* bvl = bv  + (size_t)l*1536;
    const float* bol = bo  + (size_t)l*1536;
    const float* bil = bi  + (size_t)l*3072;
    const float* bo2l= bo2 + (size_t)l*1536;
    const float* g1  = l1s + (size_t)l*1536;
    const float* be1 = l1b + (size_t)l*1536;
    const float* g2  = l2s + (size_t)l*1536;
    const float* be2 = l2b + (size_t)l*1536;

    // fused QKV (V written transposed to vt in epilogue)
    tconv3<<<dim3(48,48,3), tb32, 0, stream>>>(wq, wk, wv, wt);
    concat3_k<<<6, 256, 0, stream>>>(b3, bql, bkl, bvl);
    gemm_k<0><<<dim3(36,32), 256, 0, stream>>>(xbf, wt, b3, nullptr, nullptr,
                                               vt, qkv, nullptr, 4096, 4608, 1536);

    // block-sparse attention: mids direct, edges split-K + LSE merge
    attn_k<<<624, 256, 0, stream>>>(qkv, vt, kblk, amask, ctx, pO, pm, pl);
    attn_comb_k<<<16, 256, 0, stream>>>(pO, pm, pl, ctx);

    // attention output projection (plain bf16) + fused residual LN
    tconv<<<dim3(48,48), tb32, 0, stream>>>(wo, wt, 1536, 1536);
    gemm_k<1><<<dim3(12,32), 256, 0, stream>>>(ctx, wt, bol, nullptr, nullptr,
                                               nullptr, go, nullptr, 4096, 1536, 1536);
    ln_k<1><<<4096, 256, 0, stream>>>(xf32, go, g1, be1, xf32, xbf);

    // FFN
    tconv<<<dim3(96,48), tb32, 0, stream>>>(wi, wt, 1536, 3072);
    gemm_k<2><<<dim3(24,32), 256, 0, stream>>>(xbf, wt, bil, nullptr, nullptr,
                                               nullptr, ff1, nullptr, 4096, 3072, 1536);
    tconv<<<dim3(48,96), tb32, 0, stream>>>(wo2, wt, 3072, 1536);
    gemm_k<1><<<dim3(12,32), 256, 0, stream>>>(ff1, wt, bo2l, nullptr, nullptr,
                                               nullptr, go, nullptr, 4096, 1536, 3072);
    ln_k<1><<<4096, 256, 0, stream>>>(xf32, go, g2, be2, xf32, xbf);
  }

  // ---- classifier head ----
  tconv<<<dim3(16,48), tb32, 0, stream>>>(cw1, wt, 1536, 512);
  gemm_k<3><<<dim3(4,32), 256, 0, stream>>>(xbf, wt, cb1, nullptr, nullptr,
                                            nullptr, cls1, nullptr, 4096, 512, 1536);
  tconv<<<dim3(8,16), tb32, 0, stream>>>(cw2, wt, 512, 256);
  gemm_k<4><<<dim3(2,32), 256, 0, stream>>>(cls1, wt, cb2, nullptr, nullptr,
                                            nullptr, nullptr, out, 4096, 256, 512);

  (void)in_sizes; (void)n_in; (void)out_size;
}